// Round 1
// baseline (183.567 us; speedup 1.0000x reference)
//
#include <hip/hip_runtime.h>
#include <math.h>

// ---------------------------------------------------------------------------
// Key insight: reference takes _lstm4(...)[0] -> only timestep t=0 of the
// whole stack is needed. LSTM scan is causal, so t=0 output of every layer
// depends only on x[0]. With h0=c0=0:
//   z = x0 @ Wih^T + b ;  c = sigmoid(i)*tanh(g)  (f-gate irrelevant: c0=0)
//   h = tanh_outer( sigmoid(o) * tanh(c) )
// Whole net = 4 tiny FF "LSTM cells" + 4 FC layers on [B=256] rows.
// Batch rows are independent -> one fused kernel, 4 rows per block.
// ---------------------------------------------------------------------------

// ws layout (float offsets). Weights transposed to [K][3H], f-gate dropped,
// packed gate order: i | g | o.
#define O_W1T 0        // 87  x 768
#define O_W2T 66816    // 256 x 384
#define O_W3T 165120   // 128 x 192
#define O_W4T 189696   // 64  x 96
#define O_F1T 195840   // 32  x 128
#define O_F2T 199936   // 128 x 64
#define O_F3T 208128   // 64  x 32
#define O_B1  210176   // 768
#define O_B2  210944   // 384
#define O_B3  211328   // 192
#define O_B4  211520   // 96
// total 211616 floats = 846,464 bytes of d_ws

__global__ __launch_bounds__(256) void prep_kernel(
    const float* __restrict__ w1i, const float* __restrict__ w2i,
    const float* __restrict__ w3i, const float* __restrict__ w4i,
    const float* __restrict__ b1,  const float* __restrict__ b2,
    const float* __restrict__ b3,  const float* __restrict__ b4,
    const float* __restrict__ f1w, const float* __restrict__ f2w,
    const float* __restrict__ f3w, float* __restrict__ ws)
{
    int i = blockIdx.x * 256 + threadIdx.x;
    if (i < 89088) {                                   // w1i [1024 x 87], H=256
        int row = i / 87, k = i - row * 87;
        int g = row >> 8;
        if (g != 1) {
            int base = (g == 0) ? 0 : (g == 2) ? 256 : 512;
            ws[O_W1T + k * 768 + base + (row & 255)] = w1i[i];
        }
    } else if (i < 220160) {                           // w2i [512 x 256], H=128
        int l = i - 89088;
        int row = l >> 8, k = l & 255;
        int g = row >> 7;
        if (g != 1) {
            int base = (g == 0) ? 0 : (g == 2) ? 128 : 256;
            ws[O_W2T + k * 384 + base + (row & 127)] = w2i[l];
        }
    } else if (i < 252928) {                           // w3i [256 x 128], H=64
        int l = i - 220160;
        int row = l >> 7, k = l & 127;
        int g = row >> 6;
        if (g != 1) {
            int base = (g == 0) ? 0 : (g == 2) ? 64 : 128;
            ws[O_W3T + k * 192 + base + (row & 63)] = w3i[l];
        }
    } else if (i < 261120) {                           // w4i [128 x 64], H=32
        int l = i - 252928;
        int row = l >> 6, k = l & 63;
        int g = row >> 5;
        if (g != 1) {
            int base = (g == 0) ? 0 : (g == 2) ? 32 : 64;
            ws[O_W4T + k * 96 + base + (row & 31)] = w4i[l];
        }
    } else if (i < 262144) {                           // b1 [1024]
        int l = i - 261120;
        int g = l >> 8;
        if (g != 1) {
            int base = (g == 0) ? 0 : (g == 2) ? 256 : 512;
            ws[O_B1 + base + (l & 255)] = b1[l];
        }
    } else if (i < 262656) {                           // b2 [512]
        int l = i - 262144;
        int g = l >> 7;
        if (g != 1) {
            int base = (g == 0) ? 0 : (g == 2) ? 128 : 256;
            ws[O_B2 + base + (l & 127)] = b2[l];
        }
    } else if (i < 262912) {                           // b3 [256]
        int l = i - 262656;
        int g = l >> 6;
        if (g != 1) {
            int base = (g == 0) ? 0 : (g == 2) ? 64 : 128;
            ws[O_B3 + base + (l & 63)] = b3[l];
        }
    } else if (i < 263040) {                           // b4 [128]
        int l = i - 262912;
        int g = l >> 5;
        if (g != 1) {
            int base = (g == 0) ? 0 : (g == 2) ? 32 : 64;
            ws[O_B4 + base + (l & 31)] = b4[l];
        }
    } else if (i < 267136) {                           // f1w [128 x 32]
        int l = i - 263040;
        int j = l >> 5, k = l & 31;
        ws[O_F1T + k * 128 + j] = f1w[l];
    } else if (i < 275328) {                           // f2w [64 x 128]
        int l = i - 267136;
        int j = l >> 7, k = l & 127;
        ws[O_F2T + k * 64 + j] = f2w[l];
    } else if (i < 277376) {                           // f3w [32 x 64]
        int l = i - 275328;
        int j = l >> 6, k = l & 63;
        ws[O_F3T + k * 32 + j] = f3w[l];
    }
}

__device__ __forceinline__ float frcp(float x) { return __builtin_amdgcn_rcpf(x); }
__device__ __forceinline__ float sigm(float x) { return frcp(1.0f + __expf(-x)); }
__device__ __forceinline__ float tanh_f(float x) { return 1.0f - 2.0f * frcp(1.0f + __expf(2.0f * x)); }
// LSTM cell output at t=0 (f-gate skipped; outer tanh folded in):
__device__ __forceinline__ float cell(float zi, float zg, float zo) {
    float c = sigm(zi) * tanh_f(zg);
    return tanh_f(sigm(zo) * tanh_f(c));
}

__global__ __launch_bounds__(256) void lstm_fused(
    const float* __restrict__ x, const float* __restrict__ ws,
    const float* __restrict__ f1b, const float* __restrict__ f2b,
    const float* __restrict__ f3b, const float* __restrict__ f4w,
    const float* __restrict__ f4b, float* __restrict__ out)
{
    const int t = threadIdx.x;
    const int r0 = blockIdx.x * 4;     // 4 batch rows per block, 64 blocks

    // LDS intermediates in [k][row] layout -> per-k operands are one
    // broadcast ds_read_b128/b64 for all rows.
    __shared__ __align__(16) float xsT[87][4];
    __shared__ __align__(16) float h1T[256][4];
    __shared__ __align__(16) float h2T[128][4];
    __shared__ __align__(16) float h3T[64][4];
    __shared__ __align__(16) float h4T[32][4];
    __shared__ __align__(16) float a1T[128][4];
    __shared__ __align__(16) float a2T[64][4];
    __shared__ __align__(16) float a3T[32][4];

    const float* W1T = ws + O_W1T;
    const float* W2T = ws + O_W2T;
    const float* W3T = ws + O_W3T;
    const float* W4T = ws + O_W4T;
    const float* F1T = ws + O_F1T;
    const float* F2T = ws + O_F2T;
    const float* F3T = ws + O_F3T;
    const float* B1p = ws + O_B1;
    const float* B2p = ws + O_B2;
    const float* B3p = ws + O_B3;
    const float* B4p = ws + O_B4;

    // stage 0: load x[0] rows r0..r0+3 (87 feats each)
    for (int idx = t; idx < 348; idx += 256) {
        int r = idx & 3, k = idx >> 2;
        xsT[k][r] = x[(r0 + r) * 87 + k];
    }
    __syncthreads();

    // ---- LSTM1: 87 -> H=256. thread t owns h-column t, all 4 rows ----
    {
        float zi0, zi1, zi2, zi3, zg0, zg1, zg2, zg3, zo0, zo1, zo2, zo3;
        const float bi = B1p[t], bg = B1p[256 + t], bo = B1p[512 + t];
        zi0 = zi1 = zi2 = zi3 = bi;
        zg0 = zg1 = zg2 = zg3 = bg;
        zo0 = zo1 = zo2 = zo3 = bo;
        const float* w1 = W1T + t;
        #pragma unroll 8
        for (int k = 0; k < 87; ++k) {
            const float wi = w1[k * 768];
            const float wg = w1[k * 768 + 256];
            const float wo = w1[k * 768 + 512];
            const float4 xv = *(const float4*)(xsT[k]);
            zi0 = fmaf(xv.x, wi, zi0); zi1 = fmaf(xv.y, wi, zi1);
            zi2 = fmaf(xv.z, wi, zi2); zi3 = fmaf(xv.w, wi, zi3);
            zg0 = fmaf(xv.x, wg, zg0); zg1 = fmaf(xv.y, wg, zg1);
            zg2 = fmaf(xv.z, wg, zg2); zg3 = fmaf(xv.w, wg, zg3);
            zo0 = fmaf(xv.x, wo, zo0); zo1 = fmaf(xv.y, wo, zo1);
            zo2 = fmaf(xv.z, wo, zo2); zo3 = fmaf(xv.w, wo, zo3);
        }
        float4 hv;
        hv.x = cell(zi0, zg0, zo0);
        hv.y = cell(zi1, zg1, zo1);
        hv.z = cell(zi2, zg2, zo2);
        hv.w = cell(zi3, zg3, zo3);
        *(float4*)(h1T[t]) = hv;
    }
    __syncthreads();

    // ---- LSTM2: 256 -> H=128. col j=t&127; half t>>7 owns 2 rows ----
    {
        const int j = t & 127, half = t >> 7;
        float zi0, zi1, zg0, zg1, zo0, zo1;
        zi0 = zi1 = B2p[j];
        zg0 = zg1 = B2p[128 + j];
        zo0 = zo1 = B2p[256 + j];
        const float* w2 = W2T + j;
        const float* hp = &h1T[0][half * 2];
        #pragma unroll 16
        for (int k = 0; k < 256; ++k) {
            const float wi = w2[k * 384];
            const float wg = w2[k * 384 + 128];
            const float wo = w2[k * 384 + 256];
            const float2 hv = *(const float2*)(hp + k * 4);
            zi0 = fmaf(hv.x, wi, zi0); zi1 = fmaf(hv.y, wi, zi1);
            zg0 = fmaf(hv.x, wg, zg0); zg1 = fmaf(hv.y, wg, zg1);
            zo0 = fmaf(hv.x, wo, zo0); zo1 = fmaf(hv.y, wo, zo1);
        }
        float2 r;
        r.x = cell(zi0, zg0, zo0);
        r.y = cell(zi1, zg1, zo1);
        *(float2*)(&h2T[j][half * 2]) = r;
    }
    __syncthreads();

    // ---- LSTM3: 128 -> H=64. col j=t&63, row r=t>>6 ----
    {
        const int j = t & 63, r = t >> 6;
        float zi = B3p[j], zg = B3p[64 + j], zo = B3p[128 + j];
        const float* w3 = W3T + j;
        #pragma unroll 16
        for (int k = 0; k < 128; ++k) {
            const float hv = h2T[k][r];
            zi = fmaf(hv, w3[k * 192], zi);
            zg = fmaf(hv, w3[k * 192 + 64], zg);
            zo = fmaf(hv, w3[k * 192 + 128], zo);
        }
        h3T[j][r] = cell(zi, zg, zo);
    }
    __syncthreads();

    // ---- LSTM4: 64 -> H=32. threads 0..127: col j=t&31, row r=t>>5 ----
    if (t < 128) {
        const int j = t & 31, r = t >> 5;
        float zi = B4p[j], zg = B4p[32 + j], zo = B4p[64 + j];
        const float* w4 = W4T + j;
        #pragma unroll 16
        for (int k = 0; k < 64; ++k) {
            const float hv = h3T[k][r];
            zi = fmaf(hv, w4[k * 96], zi);
            zg = fmaf(hv, w4[k * 96 + 32], zg);
            zo = fmaf(hv, w4[k * 96 + 64], zo);
        }
        h4T[j][r] = cell(zi, zg, zo);
    }
    __syncthreads();

    // ---- FC1: 32 -> 128, relu ----
    {
        const int j = t & 127, half = t >> 7;
        float a0 = f1b[j], a1v = f1b[j];
        #pragma unroll
        for (int k = 0; k < 32; ++k) {
            const float w = F1T[k * 128 + j];
            const float2 hv = *(const float2*)(&h4T[k][half * 2]);
            a0  = fmaf(hv.x, w, a0);
            a1v = fmaf(hv.y, w, a1v);
        }
        float2 r;
        r.x = fmaxf(a0, 0.0f);
        r.y = fmaxf(a1v, 0.0f);
        *(float2*)(&a1T[j][half * 2]) = r;
    }
    __syncthreads();

    // ---- FC2: 128 -> 64, relu ----
    {
        const int j = t & 63, r = t >> 6;
        float a = f2b[j];
        #pragma unroll 16
        for (int k = 0; k < 128; ++k)
            a = fmaf(a1T[k][r], F2T[k * 64 + j], a);
        a2T[j][r] = fmaxf(a, 0.0f);
    }
    __syncthreads();

    // ---- FC3: 64 -> 32, relu ----
    if (t < 128) {
        const int j = t & 31, r = t >> 5;
        float a = f3b[j];
        #pragma unroll 16
        for (int k = 0; k < 64; ++k)
            a = fmaf(a2T[k][r], F3T[k * 32 + j], a);
        a3T[j][r] = fmaxf(a, 0.0f);
    }
    __syncthreads();

    // ---- FC4: 32 -> 3 (no relu) ----
    if (t < 16) {
        const int r = t >> 2, o = t & 3;
        if (o < 3) {
            float a = f4b[o];
            #pragma unroll
            for (int k = 0; k < 32; ++k)
                a = fmaf(a3T[k][r], f4w[o * 32 + k], a);
            out[(r0 + r) * 3 + o] = a;
        }
    }
}

extern "C" void kernel_launch(void* const* d_in, const int* in_sizes, int n_in,
                              void* d_out, int out_size, void* d_ws, size_t ws_size,
                              hipStream_t stream) {
    const float* x   = (const float*)d_in[0];
    const float* w1i = (const float*)d_in[1];
    const float* b1  = (const float*)d_in[3];
    const float* w2i = (const float*)d_in[4];
    const float* b2  = (const float*)d_in[6];
    const float* w3i = (const float*)d_in[7];
    const float* b3  = (const float*)d_in[9];
    const float* w4i = (const float*)d_in[10];
    const float* b4  = (const float*)d_in[12];
    const float* f1w = (const float*)d_in[13];
    const float* f1b = (const float*)d_in[14];
    const float* f2w = (const float*)d_in[15];
    const float* f2b = (const float*)d_in[16];
    const float* f3w = (const float*)d_in[17];
    const float* f3b = (const float*)d_in[18];
    const float* f4w = (const float*)d_in[19];
    const float* f4b = (const float*)d_in[20];
    float* ws  = (float*)d_ws;
    float* out = (float*)d_out;

    // repack weights (transpose + drop f-gate): 277,376 src elements
    prep_kernel<<<1084, 256, 0, stream>>>(w1i, w2i, w3i, w4i, b1, b2, b3, b4,
                                          f1w, f2w, f3w, ws);
    // fused forward: 64 blocks x 4 batch rows
    lstm_fused<<<64, 256, 0, stream>>>(x, ws, f1b, f2b, f3b, f4w, f4b, out);
}

// Round 2
// 173.186 us; speedup vs baseline: 1.0599x; 1.0599x over previous
//
#include <hip/hip_runtime.h>
#include <math.h>

// ---------------------------------------------------------------------------
// Reference takes _lstm4(...)[0] -> only t=0 of the whole stack matters.
// With h0=c0=0 each layer is feed-forward: z = x0 @ Wih^T + b,
// c = sigmoid(i)*tanh(g) (f-gate multiplies c0=0 -> dropped),
// h = tanh(sigmoid(o)*tanh(c)).
// R2: 256 blocks x 1 batch row (all CUs), split-K on narrow layers so the
// longest per-thread loop is 128 iters (was 256), partials reduced in LDS.
// ---------------------------------------------------------------------------

// ws layout (float offsets). Weights transposed to [K][3H], f-gate dropped,
// packed gate order: i | g | o.
#define O_W1T 0        // 87  x 768
#define O_W2T 66816    // 256 x 384
#define O_W3T 165120   // 128 x 192
#define O_W4T 189696   // 64  x 96
#define O_F1T 195840   // 32  x 128
#define O_F2T 199936   // 128 x 64
#define O_F3T 208128   // 64  x 32
#define O_B1  210176   // 768
#define O_B2  210944   // 384
#define O_B3  211328   // 192
#define O_B4  211520   // 96

__global__ __launch_bounds__(256) void prep_kernel(
    const float* __restrict__ w1i, const float* __restrict__ w2i,
    const float* __restrict__ w3i, const float* __restrict__ w4i,
    const float* __restrict__ b1,  const float* __restrict__ b2,
    const float* __restrict__ b3,  const float* __restrict__ b4,
    const float* __restrict__ f1w, const float* __restrict__ f2w,
    const float* __restrict__ f3w, float* __restrict__ ws)
{
    int i = blockIdx.x * 256 + threadIdx.x;
    if (i < 89088) {                                   // w1i [1024 x 87], H=256
        int row = i / 87, k = i - row * 87;
        int g = row >> 8;
        if (g != 1) {
            int base = (g == 0) ? 0 : (g == 2) ? 256 : 512;
            ws[O_W1T + k * 768 + base + (row & 255)] = w1i[i];
        }
    } else if (i < 220160) {                           // w2i [512 x 256], H=128
        int l = i - 89088;
        int row = l >> 8, k = l & 255;
        int g = row >> 7;
        if (g != 1) {
            int base = (g == 0) ? 0 : (g == 2) ? 128 : 256;
            ws[O_W2T + k * 384 + base + (row & 127)] = w2i[l];
        }
    } else if (i < 252928) {                           // w3i [256 x 128], H=64
        int l = i - 220160;
        int row = l >> 7, k = l & 127;
        int g = row >> 6;
        if (g != 1) {
            int base = (g == 0) ? 0 : (g == 2) ? 64 : 128;
            ws[O_W3T + k * 192 + base + (row & 63)] = w3i[l];
        }
    } else if (i < 261120) {                           // w4i [128 x 64], H=32
        int l = i - 252928;
        int row = l >> 6, k = l & 63;
        int g = row >> 5;
        if (g != 1) {
            int base = (g == 0) ? 0 : (g == 2) ? 32 : 64;
            ws[O_W4T + k * 96 + base + (row & 31)] = w4i[l];
        }
    } else if (i < 262144) {                           // b1 [1024]
        int l = i - 261120;
        int g = l >> 8;
        if (g != 1) {
            int base = (g == 0) ? 0 : (g == 2) ? 256 : 512;
            ws[O_B1 + base + (l & 255)] = b1[l];
        }
    } else if (i < 262656) {                           // b2 [512]
        int l = i - 262144;
        int g = l >> 7;
        if (g != 1) {
            int base = (g == 0) ? 0 : (g == 2) ? 128 : 256;
            ws[O_B2 + base + (l & 127)] = b2[l];
        }
    } else if (i < 262912) {                           // b3 [256]
        int l = i - 262656;
        int g = l >> 6;
        if (g != 1) {
            int base = (g == 0) ? 0 : (g == 2) ? 64 : 128;
            ws[O_B3 + base + (l & 63)] = b3[l];
        }
    } else if (i < 263040) {                           // b4 [128]
        int l = i - 262912;
        int g = l >> 5;
        if (g != 1) {
            int base = (g == 0) ? 0 : (g == 2) ? 32 : 64;
            ws[O_B4 + base + (l & 31)] = b4[l];
        }
    } else if (i < 267136) {                           // f1w [128 x 32]
        int l = i - 263040;
        int j = l >> 5, k = l & 31;
        ws[O_F1T + k * 128 + j] = f1w[l];
    } else if (i < 275328) {                           // f2w [64 x 128]
        int l = i - 267136;
        int j = l >> 7, k = l & 127;
        ws[O_F2T + k * 64 + j] = f2w[l];
    } else if (i < 277376) {                           // f3w [32 x 64]
        int l = i - 275328;
        int j = l >> 6, k = l & 63;
        ws[O_F3T + k * 32 + j] = f3w[l];
    }
}

__device__ __forceinline__ float frcp(float x) { return __builtin_amdgcn_rcpf(x); }
__device__ __forceinline__ float sigm(float x) { return frcp(1.0f + __expf(-x)); }
__device__ __forceinline__ float tanh_f(float x) { return 1.0f - 2.0f * frcp(1.0f + __expf(2.0f * x)); }
__device__ __forceinline__ float cell(float zi, float zg, float zo) {
    float c = sigm(zi) * tanh_f(zg);
    return tanh_f(sigm(zo) * tanh_f(c));
}

__global__ __launch_bounds__(256) void lstm_fused(
    const float* __restrict__ x, const float* __restrict__ ws,
    const float* __restrict__ f1b, const float* __restrict__ f2b,
    const float* __restrict__ f3b, const float* __restrict__ f4w,
    const float* __restrict__ f4b, float* __restrict__ out)
{
    const int t = threadIdx.x;
    const int r = blockIdx.x;                 // one batch row per block

    __shared__ float xs[87];
    __shared__ float h1[256], h2[128], h3[64], h4[32];
    __shared__ float a1[128], a2[64], a3[32];
    __shared__ float ps[768];                 // split-K partials, reused

    const float* W1T = ws + O_W1T;
    const float* W2T = ws + O_W2T;
    const float* W3T = ws + O_W3T;
    const float* W4T = ws + O_W4T;
    const float* F1T = ws + O_F1T;
    const float* F2T = ws + O_F2T;
    const float* F3T = ws + O_F3T;
    const float* B1p = ws + O_B1;
    const float* B2p = ws + O_B2;
    const float* B3p = ws + O_B3;
    const float* B4p = ws + O_B4;

    if (t < 87) xs[t] = x[r * 87 + t];
    __syncthreads();

    // ---- LSTM1: 87 -> 256. thread t = column t ----
    {
        float zi = B1p[t], zg = B1p[256 + t], zo = B1p[512 + t];
        const float* w = W1T + t;
        #pragma unroll 8
        for (int k = 0; k < 87; ++k) {
            const float xv = xs[k];
            zi = fmaf(xv, w[k * 768],       zi);
            zg = fmaf(xv, w[k * 768 + 256], zg);
            zo = fmaf(xv, w[k * 768 + 512], zo);
        }
        h1[t] = cell(zi, zg, zo);
    }
    __syncthreads();

    // ---- LSTM2: 256 -> 128, 2-way split-K ----
    {
        const int j = t & 127, q = t >> 7;
        float zi = q ? 0.0f : B2p[j];
        float zg = q ? 0.0f : B2p[128 + j];
        float zo = q ? 0.0f : B2p[256 + j];
        const float* w = W2T + j;
        const int k0 = q * 128;
        #pragma unroll 8
        for (int k = k0; k < k0 + 128; ++k) {
            const float hv = h1[k];
            zi = fmaf(hv, w[k * 384],       zi);
            zg = fmaf(hv, w[k * 384 + 128], zg);
            zo = fmaf(hv, w[k * 384 + 256], zo);
        }
        ps[q * 384 + j]       = zi;
        ps[q * 384 + 128 + j] = zg;
        ps[q * 384 + 256 + j] = zo;
    }
    __syncthreads();
    if (t < 128)
        h2[t] = cell(ps[t] + ps[384 + t],
                     ps[128 + t] + ps[512 + t],
                     ps[256 + t] + ps[640 + t]);
    __syncthreads();

    // ---- LSTM3: 128 -> 64, 4-way split-K ----
    {
        const int j = t & 63, q = t >> 6;
        float zi = q ? 0.0f : B3p[j];
        float zg = q ? 0.0f : B3p[64 + j];
        float zo = q ? 0.0f : B3p[128 + j];
        const float* w = W3T + j;
        const int k0 = q * 32;
        #pragma unroll 8
        for (int k = k0; k < k0 + 32; ++k) {
            const float hv = h2[k];
            zi = fmaf(hv, w[k * 192],       zi);
            zg = fmaf(hv, w[k * 192 + 64],  zg);
            zo = fmaf(hv, w[k * 192 + 128], zo);
        }
        ps[q * 192 + j]       = zi;
        ps[q * 192 + 64 + j]  = zg;
        ps[q * 192 + 128 + j] = zo;
    }
    __syncthreads();
    if (t < 64) {
        float zi = 0.0f, zg = 0.0f, zo = 0.0f;
        #pragma unroll
        for (int q = 0; q < 4; ++q) {
            zi += ps[q * 192 + t];
            zg += ps[q * 192 + 64 + t];
            zo += ps[q * 192 + 128 + t];
        }
        h3[t] = cell(zi, zg, zo);
    }
    __syncthreads();

    // ---- LSTM4: 64 -> 32, 8-way split-K ----
    {
        const int j = t & 31, q = t >> 5;
        float zi = (q == 0) ? B4p[j] : 0.0f;
        float zg = (q == 0) ? B4p[32 + j] : 0.0f;
        float zo = (q == 0) ? B4p[64 + j] : 0.0f;
        const float* w = W4T + j;
        const int k0 = q * 8;
        #pragma unroll
        for (int k = k0; k < k0 + 8; ++k) {
            const float hv = h3[k];
            zi = fmaf(hv, w[k * 96],      zi);
            zg = fmaf(hv, w[k * 96 + 32], zg);
            zo = fmaf(hv, w[k * 96 + 64], zo);
        }
        ps[q * 96 + j]      = zi;
        ps[q * 96 + 32 + j] = zg;
        ps[q * 96 + 64 + j] = zo;
    }
    __syncthreads();
    if (t < 32) {
        float zi = 0.0f, zg = 0.0f, zo = 0.0f;
        #pragma unroll
        for (int q = 0; q < 8; ++q) {
            zi += ps[q * 96 + t];
            zg += ps[q * 96 + 32 + t];
            zo += ps[q * 96 + 64 + t];
        }
        h4[t] = cell(zi, zg, zo);
    }
    __syncthreads();

    // ---- FC1: 32 -> 128, relu, 2-way split-K ----
    {
        const int j = t & 127, q = t >> 7;
        float a = q ? 0.0f : f1b[j];
        const int k0 = q * 16;
        #pragma unroll
        for (int k = k0; k < k0 + 16; ++k)
            a = fmaf(h4[k], F1T[k * 128 + j], a);
        ps[q * 128 + j] = a;
    }
    __syncthreads();
    if (t < 128) a1[t] = fmaxf(ps[t] + ps[128 + t], 0.0f);
    __syncthreads();

    // ---- FC2: 128 -> 64, relu, 4-way split-K ----
    {
        const int j = t & 63, q = t >> 6;
        float a = q ? 0.0f : f2b[j];
        const int k0 = q * 32;
        #pragma unroll 8
        for (int k = k0; k < k0 + 32; ++k)
            a = fmaf(a1[k], F2T[k * 64 + j], a);
        ps[q * 64 + j] = a;
    }
    __syncthreads();
    if (t < 64)
        a2[t] = fmaxf(ps[t] + ps[64 + t] + ps[128 + t] + ps[192 + t], 0.0f);
    __syncthreads();

    // ---- FC3: 64 -> 32, relu, 8-way split-K ----
    {
        const int j = t & 31, q = t >> 5;
        float a = (q == 0) ? f3b[j] : 0.0f;
        const int k0 = q * 8;
        #pragma unroll
        for (int k = k0; k < k0 + 8; ++k)
            a = fmaf(a2[k], F3T[k * 32 + j], a);
        ps[q * 32 + j] = a;
    }
    __syncthreads();
    if (t < 32) {
        float a = 0.0f;
        #pragma unroll
        for (int q = 0; q < 8; ++q) a += ps[q * 32 + t];
        a3[t] = fmaxf(a, 0.0f);
    }
    __syncthreads();

    // ---- FC4: 32 -> 3 ----
    if (t < 3) {
        float a = f4b[t];
        const float* w = f4w + t * 32;
        #pragma unroll 8
        for (int k = 0; k < 32; ++k)
            a = fmaf(a3[k], w[k], a);
        out[r * 3 + t] = a;
    }
}

extern "C" void kernel_launch(void* const* d_in, const int* in_sizes, int n_in,
                              void* d_out, int out_size, void* d_ws, size_t ws_size,
                              hipStream_t stream) {
    const float* x   = (const float*)d_in[0];
    const float* w1i = (const float*)d_in[1];
    const float* b1  = (const float*)d_in[3];
    const float* w2i = (const float*)d_in[4];
    const float* b2  = (const float*)d_in[6];
    const float* w3i = (const float*)d_in[7];
    const float* b3  = (const float*)d_in[9];
    const float* w4i = (const float*)d_in[10];
    const float* b4  = (const float*)d_in[12];
    const float* f1w = (const float*)d_in[13];
    const float* f1b = (const float*)d_in[14];
    const float* f2w = (const float*)d_in[15];
    const float* f2b = (const float*)d_in[16];
    const float* f3w = (const float*)d_in[17];
    const float* f3b = (const float*)d_in[18];
    const float* f4w = (const float*)d_in[19];
    const float* f4b = (const float*)d_in[20];
    float* ws  = (float*)d_ws;
    float* out = (float*)d_out;

    prep_kernel<<<1084, 256, 0, stream>>>(w1i, w2i, w3i, w4i, b1, b2, b3, b4,
                                          f1w, f2w, f3w, ws);
    // one batch row per block -> all 256 CUs active
    lstm_fused<<<256, 256, 0, stream>>>(x, ws, f1b, f2b, f3b, f4w, f4b, out);
}

// Round 4
// 162.988 us; speedup vs baseline: 1.1263x; 1.0626x over previous
//
#include <hip/hip_runtime.h>
#include <math.h>

// ---------------------------------------------------------------------------
// Reference takes _lstm4(...)[0] -> only t=0 of the whole stack matters.
// With h0=c0=0 each layer is feed-forward: z = x0 @ Wih^T + b,
// c = sigmoid(i)*tanh(g) (f-gate multiplies c0=0 -> dropped),
// h = tanh(sigmoid(o)*tanh(c)).
// R3 (resubmit; R3 bench was GPUAcquisitionTimeout): 512 threads/block
// (2 waves/SIMD -> latency hiding), split-K deepened 2x on every layer;
// critical path 311 -> ~188 loop iterations.
// ---------------------------------------------------------------------------

// ws layout (float offsets). Weights transposed to [K][3H], f-gate dropped,
// packed gate order: i | g | o.
#define O_W1T 0        // 87  x 768
#define O_W2T 66816    // 256 x 384
#define O_W3T 165120   // 128 x 192
#define O_W4T 189696   // 64  x 96
#define O_F1T 195840   // 32  x 128
#define O_F2T 199936   // 128 x 64
#define O_F3T 208128   // 64  x 32
#define O_B1  210176   // 768
#define O_B2  210944   // 384
#define O_B3  211328   // 192
#define O_B4  211520   // 96

__global__ __launch_bounds__(256) void prep_kernel(
    const float* __restrict__ w1i, const float* __restrict__ w2i,
    const float* __restrict__ w3i, const float* __restrict__ w4i,
    const float* __restrict__ b1,  const float* __restrict__ b2,
    const float* __restrict__ b3,  const float* __restrict__ b4,
    const float* __restrict__ f1w, const float* __restrict__ f2w,
    const float* __restrict__ f3w, float* __restrict__ ws)
{
    int i = blockIdx.x * 256 + threadIdx.x;
    if (i < 89088) {                                   // w1i [1024 x 87], H=256
        int row = i / 87, k = i - row * 87;
        int g = row >> 8;
        if (g != 1) {
            int base = (g == 0) ? 0 : (g == 2) ? 256 : 512;
            ws[O_W1T + k * 768 + base + (row & 255)] = w1i[i];
        }
    } else if (i < 220160) {                           // w2i [512 x 256], H=128
        int l = i - 89088;
        int row = l >> 8, k = l & 255;
        int g = row >> 7;
        if (g != 1) {
            int base = (g == 0) ? 0 : (g == 2) ? 128 : 256;
            ws[O_W2T + k * 384 + base + (row & 127)] = w2i[l];
        }
    } else if (i < 252928) {                           // w3i [256 x 128], H=64
        int l = i - 220160;
        int row = l >> 7, k = l & 127;
        int g = row >> 6;
        if (g != 1) {
            int base = (g == 0) ? 0 : (g == 2) ? 64 : 128;
            ws[O_W3T + k * 192 + base + (row & 63)] = w3i[l];
        }
    } else if (i < 261120) {                           // w4i [128 x 64], H=32
        int l = i - 252928;
        int row = l >> 6, k = l & 63;
        int g = row >> 5;
        if (g != 1) {
            int base = (g == 0) ? 0 : (g == 2) ? 32 : 64;
            ws[O_W4T + k * 96 + base + (row & 31)] = w4i[l];
        }
    } else if (i < 262144) {                           // b1 [1024]
        int l = i - 261120;
        int g = l >> 8;
        if (g != 1) {
            int base = (g == 0) ? 0 : (g == 2) ? 256 : 512;
            ws[O_B1 + base + (l & 255)] = b1[l];
        }
    } else if (i < 262656) {                           // b2 [512]
        int l = i - 262144;
        int g = l >> 7;
        if (g != 1) {
            int base = (g == 0) ? 0 : (g == 2) ? 128 : 256;
            ws[O_B2 + base + (l & 127)] = b2[l];
        }
    } else if (i < 262912) {                           // b3 [256]
        int l = i - 262656;
        int g = l >> 6;
        if (g != 1) {
            int base = (g == 0) ? 0 : (g == 2) ? 64 : 128;
            ws[O_B3 + base + (l & 63)] = b3[l];
        }
    } else if (i < 263040) {                           // b4 [128]
        int l = i - 262912;
        int g = l >> 5;
        if (g != 1) {
            int base = (g == 0) ? 0 : (g == 2) ? 32 : 64;
            ws[O_B4 + base + (l & 31)] = b4[l];
        }
    } else if (i < 267136) {                           // f1w [128 x 32]
        int l = i - 263040;
        int j = l >> 5, k = l & 31;
        ws[O_F1T + k * 128 + j] = f1w[l];
    } else if (i < 275328) {                           // f2w [64 x 128]
        int l = i - 267136;
        int j = l >> 7, k = l & 127;
        ws[O_F2T + k * 64 + j] = f2w[l];
    } else if (i < 277376) {                           // f3w [32 x 64]
        int l = i - 275328;
        int j = l >> 6, k = l & 63;
        ws[O_F3T + k * 32 + j] = f3w[l];
    }
}

__device__ __forceinline__ float frcp(float x) { return __builtin_amdgcn_rcpf(x); }
__device__ __forceinline__ float sigm(float x) { return frcp(1.0f + __expf(-x)); }
__device__ __forceinline__ float tanh_f(float x) { return 1.0f - 2.0f * frcp(1.0f + __expf(2.0f * x)); }
__device__ __forceinline__ float cell(float zi, float zg, float zo) {
    float c = sigm(zi) * tanh_f(zg);
    return tanh_f(sigm(zo) * tanh_f(c));
}

__global__ __launch_bounds__(512) void lstm_fused(
    const float* __restrict__ x, const float* __restrict__ ws,
    const float* __restrict__ f1b, const float* __restrict__ f2b,
    const float* __restrict__ f3b, const float* __restrict__ f4w,
    const float* __restrict__ f4b, float* __restrict__ out)
{
    const int t = threadIdx.x;
    const int r = blockIdx.x;                 // one batch row per block

    __shared__ float xs[87];
    __shared__ float h1[256], h2[128], h3[64], h4[32];
    __shared__ float a1[128], a2[64], a3[32];
    __shared__ float ps[1536];                // split-K partials, reused

    const float* W1T = ws + O_W1T;
    const float* W2T = ws + O_W2T;
    const float* W3T = ws + O_W3T;
    const float* W4T = ws + O_W4T;
    const float* F1T = ws + O_F1T;
    const float* F2T = ws + O_F2T;
    const float* F3T = ws + O_F3T;
    const float* B1p = ws + O_B1;
    const float* B2p = ws + O_B2;
    const float* B3p = ws + O_B3;
    const float* B4p = ws + O_B4;

    if (t < 87) xs[t] = x[r * 87 + t];
    __syncthreads();

    // ---- LSTM1: 87 -> 256, 2-way split-K (44 / 43) ----
    {
        const int j = t & 255, q = t >> 8;
        float zi = q ? 0.0f : B1p[j];
        float zg = q ? 0.0f : B1p[256 + j];
        float zo = q ? 0.0f : B1p[512 + j];
        const float* w = W1T + j;
        const int k0 = q ? 44 : 0, k1 = q ? 87 : 44;
        #pragma unroll 8
        for (int k = k0; k < k1; ++k) {
            const float xv = xs[k];
            zi = fmaf(xv, w[k * 768],       zi);
            zg = fmaf(xv, w[k * 768 + 256], zg);
            zo = fmaf(xv, w[k * 768 + 512], zo);
        }
        ps[q * 768 + j]       = zi;
        ps[q * 768 + 256 + j] = zg;
        ps[q * 768 + 512 + j] = zo;
    }
    __syncthreads();
    if (t < 256)
        h1[t] = cell(ps[t] + ps[768 + t],
                     ps[256 + t] + ps[1024 + t],
                     ps[512 + t] + ps[1280 + t]);
    __syncthreads();

    // ---- LSTM2: 256 -> 128, 4-way split-K ----
    {
        const int j = t & 127, q = t >> 7;
        float zi = q ? 0.0f : B2p[j];
        float zg = q ? 0.0f : B2p[128 + j];
        float zo = q ? 0.0f : B2p[256 + j];
        const float* w = W2T + j;
        const int k0 = q * 64;
        #pragma unroll 8
        for (int k = k0; k < k0 + 64; ++k) {
            const float hv = h1[k];
            zi = fmaf(hv, w[k * 384],       zi);
            zg = fmaf(hv, w[k * 384 + 128], zg);
            zo = fmaf(hv, w[k * 384 + 256], zo);
        }
        ps[q * 384 + j]       = zi;
        ps[q * 384 + 128 + j] = zg;
        ps[q * 384 + 256 + j] = zo;
    }
    __syncthreads();
    if (t < 128) {
        float zi = 0.0f, zg = 0.0f, zo = 0.0f;
        #pragma unroll
        for (int q = 0; q < 4; ++q) {
            zi += ps[q * 384 + t];
            zg += ps[q * 384 + 128 + t];
            zo += ps[q * 384 + 256 + t];
        }
        h2[t] = cell(zi, zg, zo);
    }
    __syncthreads();

    // ---- LSTM3: 128 -> 64, 8-way split-K ----
    {
        const int j = t & 63, q = t >> 6;
        float zi = q ? 0.0f : B3p[j];
        float zg = q ? 0.0f : B3p[64 + j];
        float zo = q ? 0.0f : B3p[128 + j];
        const float* w = W3T + j;
        const int k0 = q * 16;
        #pragma unroll
        for (int k = k0; k < k0 + 16; ++k) {
            const float hv = h2[k];
            zi = fmaf(hv, w[k * 192],       zi);
            zg = fmaf(hv, w[k * 192 + 64],  zg);
            zo = fmaf(hv, w[k * 192 + 128], zo);
        }
        ps[q * 192 + j]       = zi;
        ps[q * 192 + 64 + j]  = zg;
        ps[q * 192 + 128 + j] = zo;
    }
    __syncthreads();
    if (t < 64) {
        float zi = 0.0f, zg = 0.0f, zo = 0.0f;
        #pragma unroll
        for (int q = 0; q < 8; ++q) {
            zi += ps[q * 192 + t];
            zg += ps[q * 192 + 64 + t];
            zo += ps[q * 192 + 128 + t];
        }
        h3[t] = cell(zi, zg, zo);
    }
    __syncthreads();

    // ---- LSTM4: 64 -> 32, 16-way split-K ----
    {
        const int j = t & 31, q = t >> 5;
        float zi = (q == 0) ? B4p[j] : 0.0f;
        float zg = (q == 0) ? B4p[32 + j] : 0.0f;
        float zo = (q == 0) ? B4p[64 + j] : 0.0f;
        const float* w = W4T + j;
        const int k0 = q * 4;
        #pragma unroll
        for (int k = k0; k < k0 + 4; ++k) {
            const float hv = h3[k];
            zi = fmaf(hv, w[k * 96],      zi);
            zg = fmaf(hv, w[k * 96 + 32], zg);
            zo = fmaf(hv, w[k * 96 + 64], zo);
        }
        ps[q * 96 + j]      = zi;
        ps[q * 96 + 32 + j] = zg;
        ps[q * 96 + 64 + j] = zo;
    }
    __syncthreads();
    if (t < 32) {
        float zi = 0.0f, zg = 0.0f, zo = 0.0f;
        #pragma unroll
        for (int q = 0; q < 16; ++q) {
            zi += ps[q * 96 + t];
            zg += ps[q * 96 + 32 + t];
            zo += ps[q * 96 + 64 + t];
        }
        h4[t] = cell(zi, zg, zo);
    }
    __syncthreads();

    // ---- FC1: 32 -> 128, relu, 4-way split-K ----
    {
        const int j = t & 127, q = t >> 7;
        float a = q ? 0.0f : f1b[j];
        const int k0 = q * 8;
        #pragma unroll
        for (int k = k0; k < k0 + 8; ++k)
            a = fmaf(h4[k], F1T[k * 128 + j], a);
        ps[q * 128 + j] = a;
    }
    __syncthreads();
    if (t < 128)
        a1[t] = fmaxf(ps[t] + ps[128 + t] + ps[256 + t] + ps[384 + t], 0.0f);
    __syncthreads();

    // ---- FC2: 128 -> 64, relu, 8-way split-K ----
    {
        const int j = t & 63, q = t >> 6;
        float a = q ? 0.0f : f2b[j];
        const int k0 = q * 16;
        #pragma unroll
        for (int k = k0; k < k0 + 16; ++k)
            a = fmaf(a1[k], F2T[k * 64 + j], a);
        ps[q * 64 + j] = a;
    }
    __syncthreads();
    if (t < 64) {
        float a = 0.0f;
        #pragma unroll
        for (int q = 0; q < 8; ++q) a += ps[q * 64 + t];
        a2[t] = fmaxf(a, 0.0f);
    }
    __syncthreads();

    // ---- FC3: 64 -> 32, relu, 16-way split-K ----
    {
        const int j = t & 31, q = t >> 5;
        float a = (q == 0) ? f3b[j] : 0.0f;
        const int k0 = q * 4;
        #pragma unroll
        for (int k = k0; k < k0 + 4; ++k)
            a = fmaf(a2[k], F3T[k * 32 + j], a);
        ps[q * 32 + j] = a;
    }
    __syncthreads();
    if (t < 32) {
        float a = 0.0f;
        #pragma unroll
        for (int q = 0; q < 16; ++q) a += ps[q * 32 + t];
        a3[t] = fmaxf(a, 0.0f);
    }
    __syncthreads();

    // ---- FC4: 32 -> 3 ----
    if (t < 3) {
        float a = f4b[t];
        const float* w = f4w + t * 32;
        #pragma unroll
        for (int k = 0; k < 32; ++k)
            a = fmaf(a3[k], w[k], a);
        out[r * 3 + t] = a;
    }
}

extern "C" void kernel_launch(void* const* d_in, const int* in_sizes, int n_in,
                              void* d_out, int out_size, void* d_ws, size_t ws_size,
                              hipStream_t stream) {
    const float* x   = (const float*)d_in[0];
    const float* w1i = (const float*)d_in[1];
    const float* b1  = (const float*)d_in[3];
    const float* w2i = (const float*)d_in[4];
    const float* b2  = (const float*)d_in[6];
    const float* w3i = (const float*)d_in[7];
    const float* b3  = (const float*)d_in[9];
    const float* w4i = (const float*)d_in[10];
    const float* b4  = (const float*)d_in[12];
    const float* f1w = (const float*)d_in[13];
    const float* f1b = (const float*)d_in[14];
    const float* f2w = (const float*)d_in[15];
    const float* f2b = (const float*)d_in[16];
    const float* f3w = (const float*)d_in[17];
    const float* f3b = (const float*)d_in[18];
    const float* f4w = (const float*)d_in[19];
    const float* f4b = (const float*)d_in[20];
    float* ws  = (float*)d_ws;
    float* out = (float*)d_out;

    prep_kernel<<<1084, 256, 0, stream>>>(w1i, w2i, w3i, w4i, b1, b2, b3, b4,
                                          f1w, f2w, f3w, ws);
    // one batch row per block, 512 threads (2 waves/SIMD for latency hiding)
    lstm_fused<<<256, 512, 0, stream>>>(x, ws, f1b, f2b, f3b, f4w, f4b, out);
}